// Round 11
// baseline (438.238 us; speedup 1.0000x reference)
//
#include <hip/hip_runtime.h>
#include <hip/hip_bf16.h>

#define Bb  8
#define Cc  64
#define Tt  16
#define Vv  207
#define Hh  8
#define DH  8
#define NW  4
#define WSZ 4
#define Nn  (WSZ*Vv)       // 828
#define NP  832
#define TV  (Tt*Vv)        // 3312
#define CTV (Cc*Tt*Vv)     // 211968
#define S   (Bb*CTV)       // 1695744
#define NBWH (Bb*NW*Hh)    // 256
#define EPSF 1e-5f
#define QSCALE 0.51006971401146f    // log2(e)/sqrt(8) folded into Q
#define FRAG_BWH (52*64*4)          // 13312 shorts per bwh
#define LAYER_WSZ 49152             // qkv 12288 + proj 4096 + w1 16384 + w2 16384 frags
#define NBLK 256                    // persistent grid = #CUs (MI355X rocminfo)
#define SMEM_BYTES 125696           // max stage (qkv): 24576 + 768 + 4*25088

typedef __attribute__((ext_vector_type(4))) short bf16x4;
typedef __attribute__((ext_vector_type(4))) float f32x4;
typedef __attribute__((ext_vector_type(2))) unsigned int u32x2;

static __device__ __forceinline__ short f2bf(float f) {
    union { float f; unsigned u; } v; v.f = f;
    unsigned r = (v.u + 0x7FFFu + ((v.u >> 16) & 1u)) >> 16;  // RNE
    return (short)r;
}

static __device__ __forceinline__ bf16x4 pack4(float a, float b, float c, float d) {
    unsigned ua = __builtin_bit_cast(unsigned, a) + 0x8000u;
    unsigned ub = __builtin_bit_cast(unsigned, b) + 0x8000u;
    unsigned uc = __builtin_bit_cast(unsigned, c) + 0x8000u;
    unsigned ud = __builtin_bit_cast(unsigned, d) + 0x8000u;
    u32x2 t;
    t[0] = (ua >> 16) | (ub & 0xFFFF0000u);
    t[1] = (uc >> 16) | (ud & 0xFFFF0000u);
    return __builtin_bit_cast(bf16x4, t);
}

// cubic minimax 2^x; scores |x| < ~0.25 so rel err < 1e-5 (invisible vs bf16)
static __device__ __forceinline__ float pexp2(float x) {
    float t = __builtin_fmaf(x, 0.0558263f, 0.2401536f);
    t = __builtin_fmaf(x, t, 0.6931471f);
    return __builtin_fmaf(x, t, 1.0f);
}

// device-scope generation barrier; bar[0]=count, bar[1]=gen (zeroed by prep each call)
static __device__ __forceinline__ void gsync(unsigned* bar) {
    __syncthreads();
    if (threadIdx.x == 0) {
        __threadfence();                                  // release prior writes
        unsigned gen = atomicAdd(&bar[1], 0u);
        unsigned arrived = atomicAdd(&bar[0], 1u) + 1u;
        if (arrived == (unsigned)NBLK) {
            atomicExch(&bar[0], 0u);
            __threadfence();
            atomicAdd(&bar[1], 1u);
        } else {
            while (atomicAdd(&bar[1], 0u) == gen) { __builtin_amdgcn_s_sleep(8); }
        }
        __threadfence();                                  // acquire
    }
    __syncthreads();
}

// ---------------- prep: weights->frags, q/k/v const regions, stats+bar zero ----------------
__global__ void prep_kernel(const float* __restrict__ qa, const float* __restrict__ pa,
                            const float* __restrict__ w1a, const float* __restrict__ w2a,
                            const float* __restrict__ qbw, const float* __restrict__ pbw,
                            const float* __restrict__ w1b, const float* __restrict__ w2b,
                            short* __restrict__ wf, float* __restrict__ stats,
                            unsigned* __restrict__ bar,
                            short* __restrict__ qf, short* __restrict__ kf,
                            short* __restrict__ vf) {
    int i0 = blockIdx.x*256 + threadIdx.x;
    if (i0 < 64) stats[i0] = 0.f;
    if (i0 >= 64 && i0 < 80) bar[i0-64] = 0u;
    for (int i = i0; i < 24576; i += 416*256) {
        int l = i / 12288; int f = i % 12288;
        const float* qw = l ? qbw : qa;
        const float* pw = l ? pbw : pa;
        const float* w1 = l ? w1b : w1a;
        const float* w2 = l ? w2b : w2a;
        short* dst = wf + l*LAYER_WSZ;
        bf16x4 out;
        if (f < 3072) {
            int s = f; int nt = s>>8; int kc = (s>>6)&3; int ln = s&63;
            int li = ln&15; int q = ln>>4;
            #pragma unroll
            for (int j = 0; j < 4; ++j) out[j] = f2bf(qw[(kc*16+q*4+j)*192 + nt*16+li]);
            *((bf16x4*)&dst[s*4]) = out;
        } else if (f < 4096) {
            int s = f-3072; int nt = s>>8; int kc = (s>>6)&3; int ln = s&63;
            int li = ln&15; int q = ln>>4;
            #pragma unroll
            for (int j = 0; j < 4; ++j) out[j] = f2bf(pw[(kc*16+q*4+j)*64 + nt*16+li]);
            *((bf16x4*)&dst[12288 + s*4]) = out;
        } else if (f < 8192) {
            int s = f-4096; int nt = s>>8; int kc = (s>>6)&3; int ln = s&63;
            int li = ln&15; int q = ln>>4;
            #pragma unroll
            for (int j = 0; j < 4; ++j) out[j] = f2bf(w1[(kc*16+q*4+j)*256 + nt*16+li]);
            *((bf16x4*)&dst[16384 + s*4]) = out;
        } else {
            int s = f-8192; int nt = s>>8; int ct = (s>>6)&3; int ln = s&63;
            int li = ln&15; int q = ln>>4;
            #pragma unroll
            for (int j = 0; j < 4; ++j) out[j] = f2bf(w2[(nt*16+q*4+j)*64 + ct*16+li]);
            *((bf16x4*)&dst[32768 + s*4]) = out;
        }
    }
    for (int i = i0; i < NBWH*1664; i += 416*256) {
        int bwh = i / 1664; int rest = i % 1664;
        int nt = rest >> 5; int u = rest & 31;
        size_t base = (size_t)bwh*FRAG_BWH + nt*256;
        *((u32x2*)&qf[base + (32+u)*4]) = (u32x2){0u,0u};
        *((u32x2*)&kf[base + (32+u)*4]) = (u32x2){0u,0u};
        int vlane = (u>>3)*16 + 8 + (u&7);
        short v = ((u&7) == 0) ? (short)0x3F80 : (short)0;
        bf16x4 vv4 = {v,v,v,v};
        *((bf16x4*)&vf[base + vlane*4]) = vv4;
    }
}

// ================= mega-kernel stages =================

static __device__ __forceinline__ void st_qkv(char* smem, int bid, int tid,
        const float* __restrict__ src, const float* __restrict__ st,
        const float* __restrict__ g, const float* __restrict__ be,
        const short* __restrict__ wfq, const float* __restrict__ bias,
        short* __restrict__ qf, short* __restrict__ kf, short* __restrict__ vf) {
    short* wqs = (short*)smem;                          // 24576 B
    float* bqs = (float*)(smem + 24576);                // 768 B
    int quarter = tid >> 8; int qtid = tid & 255;
    short* os = (short*)(smem + 25344) + quarter*12544; // 4 x 25088 B
    {
        const u32x2* wsrc = (const u32x2*)wfq;
        u32x2* wdst = (u32x2*)wqs;
        for (int s = tid; s < 3072; s += 1024) wdst[s] = wsrc[s];
        if (tid < 192) bqs[tid] = bias[tid];
    }
    __syncthreads();
    int qid = bid*4 + quarter;
    bool vt = qid < 416;
    int b = vt ? qid/52 : 0;
    int r0 = vt ? (qid%52)*64 : 0;
    int lane = qtid & 63; int qwv = qtid >> 6;
    int l15 = lane & 15; int quad = lane >> 4;
    if (vt) {
        const float* xb = src + (size_t)b*CTV;
        int r = r0 + qwv*16 + l15;
        int rc = (r < TV) ? r : TV-1;
        int t = rc / Vv; int vv = rc - t*Vv;
        float mean = 0.f, rstd = 0.f; int off;
        if (st) {
            mean = st[b*2] * (1.0f/CTV);
            float var = st[b*2+1] * (1.0f/CTV) - mean*mean;
            rstd = rsqrtf(var + EPSF);
            off = ((t+2)&15)*Vv + vv;            // roll(-2): read source at t+2
        } else off = rc;
        bf16x4 xf[4];
        #pragma unroll
        for (int kc = 0; kc < 4; ++kc) {
            #pragma unroll
            for (int j = 0; j < 4; ++j) {
                int idx = (kc*16 + quad*4 + j)*TV + off;
                float xv = xb[idx];
                if (st) xv = (xv - mean)*rstd*g[idx] + be[idx];
                xf[kc][j] = f2bf(xv);
            }
        }
        int pos = qwv*16 + l15;
        #pragma unroll
        for (int nt = 0; nt < 12; ++nt) {
            float4 bb = *((const float4*)&bqs[nt*16 + quad*4]);
            f32x4 acc = {bb.x, bb.y, bb.z, bb.w};
            #pragma unroll
            for (int kc = 0; kc < 4; ++kc) {
                bf16x4 wf2 = *((const bf16x4*)&wqs[((nt*4 + kc)*64 + lane)*4]);
                acc = __builtin_amdgcn_mfma_f32_16x16x16bf16_1k(wf2, xf[kc], acc, 0, 0, 0);
            }
            bf16x4 pk = (nt < 4) ? pack4(acc[0]*QSCALE, acc[1]*QSCALE, acc[2]*QSCALE, acc[3]*QSCALE)
                                 : pack4(acc[0], acc[1], acc[2], acc[3]);
            *((bf16x4*)&os[pos*196 + nt*16 + quad*4]) = pk;
        }
    }
    __syncthreads();
    if (vt) {
        int pp = qtid & 63;
        int rr = r0 + pp;
        bool pv = rr < TV;
        int rrc = pv ? rr : TV-1;
        int t4 = rrc / Vv; int vv4 = rrc - t4*Vv;
        int n2 = (t4 & 3)*Vv + vv4;
        int nt2 = n2 >> 4; int l15n = n2 & 15;
        int quadn = (n2 & 15) >> 2; int jn = n2 & 3;
        int wbase = (b*NW + (t4 >> 2))*Hh;
        if (pv) {
            #pragma unroll
            for (int i = 0; i < 2; ++i) {
                int h = i*4 + qwv;
                size_t fb = ((size_t)(wbase+h)*52 + nt2)*256;
                bf16x4 q0 = *((const bf16x4*)&os[pp*196 + h*8]);
                bf16x4 q1 = *((const bf16x4*)&os[pp*196 + h*8 + 4]);
                *((bf16x4*)&qf[fb + l15n*4])        = q0;
                *((bf16x4*)&qf[fb + (16 + l15n)*4]) = q1;
                bf16x4 k0 = *((const bf16x4*)&os[pp*196 + 64 + h*8]);
                bf16x4 k1 = *((const bf16x4*)&os[pp*196 + 64 + h*8 + 4]);
                *((bf16x4*)&kf[fb + l15n*4])        = k0;
                *((bf16x4*)&kf[fb + (16 + l15n)*4]) = k1;
            }
            #pragma unroll
            for (int i = 0; i < 16; ++i) {
                int hd = i*4 + qwv;
                int h = hd >> 3; int d = hd & 7;
                vf[(((size_t)(wbase+h)*52 + nt2)*64 + quadn*16 + d)*4 + jn]
                    = os[pp*196 + 128 + hd];
            }
        }
    }
}

static __device__ __forceinline__ void st_attn(char* smem, int bid, int tid,
        const short* __restrict__ qf, const short* __restrict__ kf,
        const short* __restrict__ vf, short* __restrict__ att) {
    short* ks2 = (short*)smem;              // 26624 B
    short* vs2 = (short*)(smem + 26624);    // 26624 B
    int bwh = bid;
    int lane = tid & 63;
    int wv = tid >> 6;
    int quad = lane >> 4;
    int l15 = lane & 15;
    {
        const u32x2* kg = (const u32x2*)(kf + (size_t)bwh*FRAG_BWH);
        const u32x2* vg = (const u32x2*)(vf + (size_t)bwh*FRAG_BWH);
        u32x2* kd = (u32x2*)ks2; u32x2* vd = (u32x2*)vs2;
        for (int idx = tid; idx < 3328; idx += 1024) { kd[idx] = kg[idx]; vd[idx] = vg[idx]; }
    }
    __syncthreads();
    int nm = (wv < 4) ? 4 : 3;
    const short* qbase = qf + (size_t)bwh*FRAG_BWH;
    bf16x4 aq[4];
    f32x4 oacc[4];
    #pragma unroll
    for (int i = 0; i < 4; ++i) {
        aq[i] = (bf16x4){0,0,0,0};
        oacc[i] = (f32x4){0.f,0.f,0.f,0.f};
        if (i < nm)
            aq[i] = *(const bf16x4*)(qbase + ((wv + 16*i)*256 + lane*4));
    }
    for (int nt = 0; nt < 52; ++nt) {
        bf16x4 ak = *(const bf16x4*)&ks2[nt*256 + lane*4];
        bf16x4 av = *(const bf16x4*)&vs2[nt*256 + lane*4];
        bool mask = (nt == 51) && (quad == 3);
        #pragma unroll
        for (int i = 0; i < 4; ++i) {
            if (i < nm) {
                f32x4 s = __builtin_amdgcn_mfma_f32_16x16x16bf16_1k(
                              ak, aq[i], (f32x4){0.f,0.f,0.f,0.f}, 0, 0, 0);
                bf16x4 pb = pack4(pexp2(s[0]), pexp2(s[1]), pexp2(s[2]), pexp2(s[3]));
                if (mask) pb = (bf16x4){0,0,0,0};
                oacc[i] = __builtin_amdgcn_mfma_f32_16x16x16bf16_1k(av, pb, oacc[i], 0, 0, 0);
            }
        }
    }
    int h = bwh & 7; int bw = bwh >> 3;
    #pragma unroll
    for (int i = 0; i < 4; ++i) {
        if (i < nm) {
            float ls = __shfl(oacc[i][0], 32 + l15, 64);   // l-sum = O row 8
            float inv = 1.f / ls;
            int m = (wv + 16*i)*16 + l15;
            if (quad < 2 && m < Nn) {
                bf16x4 ov = pack4(oacc[i][0]*inv, oacc[i][1]*inv,
                                  oacc[i][2]*inv, oacc[i][3]*inv);
                *((bf16x4*)&att[((size_t)bw*Nn + m)*Cc + h*DH + quad*4]) = ov;
            }
        }
    }
}

static __device__ __forceinline__ void st_proj(char* smem, int bid, int tid,
        const short* __restrict__ att, const short* __restrict__ wfp,
        const float* __restrict__ bo, const float* __restrict__ resid,
        const float* __restrict__ st, const float* __restrict__ g,
        const float* __restrict__ be,
        float* __restrict__ out, float* __restrict__ stats) {
    short* wos = (short*)smem;                  // 8192 B
    float* bos = (float*)(smem + 8192);         // 256 B
    float* redb = (float*)(smem + 8448);        // 8192 B
    int quarter = tid >> 8; int qtid = tid & 255;
    float* r1 = redb + quarter*512;
    float* r2 = r1 + 256;
    {
        const u32x2* wsrc = (const u32x2*)wfp;
        u32x2* wdst = (u32x2*)wos;
        if (tid < 1024) wdst[tid] = wsrc[tid];
        if (tid < 64) bos[tid] = bo[tid];
    }
    __syncthreads();
    int qid = bid*4 + quarter;
    bool vt = qid < 416;
    int b = vt ? qid/52 : 0;
    int r0 = vt ? (qid%52)*64 : 0;
    int lane = qtid & 63; int qwv = qtid >> 6;
    int l15 = lane & 15; int quad = lane >> 4;
    float s1 = 0.f, s2 = 0.f;
    if (vt) {
        const float* xb = resid + (size_t)b*CTV;
        int r = r0 + qwv*16 + l15;
        bool valid = r < TV;
        int rc = valid ? r : TV-1;
        int t = rc / Vv; int vv = rc - t*Vv;
        int n = (t & 3)*Vv + vv;
        int bw = b*NW + (t >> 2);
        const short* arow = att + ((size_t)bw*Nn + n)*Cc;
        bf16x4 af[4];
        #pragma unroll
        for (int kc = 0; kc < 4; ++kc)
            af[kc] = *((const bf16x4*)&arow[kc*16 + quad*4]);
        f32x4 acc[4];
        #pragma unroll
        for (int nt = 0; nt < 4; ++nt) {
            float4 bb = *((const float4*)&bos[nt*16 + quad*4]);
            acc[nt] = (f32x4){bb.x, bb.y, bb.z, bb.w};
            #pragma unroll
            for (int kc = 0; kc < 4; ++kc) {
                bf16x4 wf2 = *((const bf16x4*)&wos[((nt*4 + kc)*64 + lane)*4]);
                acc[nt] = __builtin_amdgcn_mfma_f32_16x16x16bf16_1k(wf2, af[kc], acc[nt], 0, 0, 0);
            }
        }
        float mean = 0.f, rstd = 0.f; int off;
        if (st) {
            mean = st[b*2] * (1.0f/CTV);
            float var = st[b*2+1] * (1.0f/CTV) - mean*mean;
            rstd = rsqrtf(var + EPSF);
            off = ((t+2)&15)*Vv + vv;
        } else off = rc;
        if (valid) {
            #pragma unroll
            for (int nt = 0; nt < 4; ++nt) {
                #pragma unroll
                for (int j = 0; j < 4; ++j) {
                    int c_out = nt*16 + quad*4 + j;
                    int ridx = c_out*TV + off;
                    float xv = xb[ridx];
                    if (st) xv = (xv - mean)*rstd*g[ridx] + be[ridx];
                    float val = acc[nt][j] + xv;
                    out[(size_t)b*CTV + (size_t)c_out*TV + r] = val;
                    s1 += val; s2 += val*val;
                }
            }
        }
    }
    r1[qtid] = s1; r2[qtid] = s2;
    __syncthreads();
    for (int o = 128; o > 0; o >>= 1) {
        if (qtid < o) { r1[qtid] += r1[qtid+o]; r2[qtid] += r2[qtid+o]; }
        __syncthreads();
    }
    if (qtid == 0 && vt) { atomicAdd(&stats[b*2], r1[0]); atomicAdd(&stats[b*2+1], r2[0]); }
}

static __device__ __forceinline__ void st_ffn(char* smem, int bid, int tid,
        const float* __restrict__ xin, const float* __restrict__ st,
        const float* __restrict__ g, const float* __restrict__ be,
        const short* __restrict__ wf1, const float* __restrict__ b1,
        const short* __restrict__ wf2g, const float* __restrict__ b2,
        float* __restrict__ out, float* __restrict__ stats) {
    short* w1s = (short*)smem;                  // 32768 B
    short* w2s = (short*)(smem + 32768);        // 32768 B
    int quarter = tid >> 8; int qtid = tid & 255;
    short* xsf = (short*)(smem + 65536) + quarter*4096;   // 4 x 8192 B
    float* b1s = (float*)(smem + 98304);        // 1024 B
    float* b2s = (float*)(smem + 99328);        // 256 B
    float* redb = (float*)(smem + 99584);       // 8192 B
    float* r1s = redb + quarter*512;
    float* r2s = r1s + 256;
    {
        const u32x2* s1p = (const u32x2*)wf1;
        const u32x2* s2p = (const u32x2*)wf2g;
        u32x2* d1 = (u32x2*)w1s; u32x2* d2 = (u32x2*)w2s;
        for (int s = tid; s < 4096; s += 1024) { d1[s] = s1p[s]; d2[s] = s2p[s]; }
        if (tid < 256) b1s[tid] = b1[tid];
        if (tid < 64) b2s[tid] = b2[tid];
    }
    int qid = bid*4 + quarter;
    bool vt = qid < 416;
    int b = vt ? qid/52 : 0;
    int r0 = vt ? (qid%52)*64 : 0;
    const float* xb = xin + (size_t)b*CTV;
    float mean = st[b*2] * (1.0f/CTV);
    float var  = st[b*2+1] * (1.0f/CTV) - mean*mean;
    float rstd = rsqrtf(var + EPSF);
    if (vt) {
        for (int s2 = qtid; s2 < 1024; s2 += 256) {
            int wv2 = s2 >> 8; int kc = (s2 >> 6) & 3; int ln = s2 & 63;
            int l15 = ln & 15; int quad = ln >> 4;
            int r = r0 + wv2*16 + l15; if (r >= TV) r = TV-1;
            bf16x4 f;
            #pragma unroll
            for (int j = 0; j < 4; ++j) {
                int idx = (kc*16 + quad*4 + j)*TV + r;
                f[j] = f2bf((xb[idx] - mean)*rstd*g[idx] + be[idx]);
            }
            *((bf16x4*)&xsf[s2*4]) = f;
        }
    }
    __syncthreads();
    int lane = qtid & 63; int qwv = qtid >> 6;
    int l15 = lane & 15; int quad = lane >> 4;
    float s1 = 0.f, s2v = 0.f;
    if (vt) {
        bf16x4 xf[4];
        #pragma unroll
        for (int kc = 0; kc < 4; ++kc)
            xf[kc] = *((const bf16x4*)&xsf[((qwv*4 + kc)*64 + lane)*4]);
        f32x4 oacc[4];
        #pragma unroll
        for (int ct = 0; ct < 4; ++ct) oacc[ct] = (f32x4){0.f,0.f,0.f,0.f};
        for (int nt = 0; nt < 16; ++nt) {
            float4 bb = *((const float4*)&b1s[nt*16 + quad*4]);
            f32x4 acc = {bb.x, bb.y, bb.z, bb.w};
            #pragma unroll
            for (int kc = 0; kc < 4; ++kc) {
                bf16x4 wfv = *((const bf16x4*)&w1s[((nt*4 + kc)*64 + lane)*4]);
                acc = __builtin_amdgcn_mfma_f32_16x16x16bf16_1k(wfv, xf[kc], acc, 0, 0, 0);
            }
            bf16x4 pf = pack4(fmaxf(acc[0], 0.f), fmaxf(acc[1], 0.f),
                              fmaxf(acc[2], 0.f), fmaxf(acc[3], 0.f));
            #pragma unroll
            for (int ct = 0; ct < 4; ++ct) {
                bf16x4 wfv2 = *((const bf16x4*)&w2s[((nt*4 + ct)*64 + lane)*4]);
                oacc[ct] = __builtin_amdgcn_mfma_f32_16x16x16bf16_1k(wfv2, pf, oacc[ct], 0, 0, 0);
            }
        }
        int r = r0 + qwv*16 + l15;
        if (r < TV) {
            #pragma unroll
            for (int ct = 0; ct < 4; ++ct) {
                #pragma unroll
                for (int j = 0; j < 4; ++j) {
                    int c_out = ct*16 + quad*4 + j;
                    int idx = c_out*TV + r;
                    float xv = (xb[idx] - mean)*rstd*g[idx] + be[idx];
                    float val = oacc[ct][j] + b2s[c_out] + xv;
                    out[(size_t)b*CTV + idx] = val;
                    s1 += val; s2v += val*val;
                }
            }
        }
    }
    r1s[qtid] = s1; r2s[qtid] = s2v;
    __syncthreads();
    for (int o = 128; o > 0; o >>= 1) {
        if (qtid < o) { r1s[qtid] += r1s[qtid+o]; r2s[qtid] += r2s[qtid+o]; }
        __syncthreads();
    }
    if (qtid == 0 && vt) { atomicAdd(&stats[b*2], r1s[0]); atomicAdd(&stats[b*2+1], r2s[0]); }
}

static __device__ __forceinline__ void st_lnfinal(int bid, int tid,
        const float* __restrict__ x, const float* __restrict__ g,
        const float* __restrict__ be, const float* __restrict__ st,
        float* __restrict__ out) {
    for (int idx = bid*1024 + tid; idx < S; idx += NBLK*1024) {
        int b = idx / CTV; int r = idx % CTV;
        int c = r / TV; int q2 = r % TV; int t = q2 / Vv; int vv = q2 % Vv;
        float mean = st[b*2] * (1.0f/CTV);
        float var  = st[b*2+1] * (1.0f/CTV) - mean*mean;
        float rstd = rsqrtf(var + EPSF);
        float val = (x[idx]-mean)*rstd*g[r] + be[r];
        int tout = (t - 2 + Tt) & 15;   // roll(-2)
        size_t oidx = ((size_t)(b*Cc + c)*Tt + tout)*Vv + vv;
        out[oidx] = val;
    }
}

// ---------------- the mega-kernel: whole forward, 9 stages, 8 grid barriers ----------------
__global__ __launch_bounds__(1024) void mega_kernel(
        const float* __restrict__ xin, float* __restrict__ bufA, float* __restrict__ bufB,
        float* __restrict__ stats, unsigned* __restrict__ bar,
        const short* __restrict__ wf, short* __restrict__ qf, short* __restrict__ kf,
        short* __restrict__ vf, short* __restrict__ att,
        const float* A1, const float* A3, const float* A5, const float* A7,
        const float* A8, const float* A9, const float* A10, const float* A11,
        const float* B1, const float* B3, const float* B5, const float* B7,
        const float* B8, const float* B9, const float* B10, const float* B11,
        float* __restrict__ dout) {
    __shared__ __align__(16) char smem[SMEM_BYTES];
    int bid = blockIdx.x; int tid = threadIdx.x;
    const short* wfA = wf;
    const short* wfB = wf + LAYER_WSZ;

    // ---- block A ----
    st_qkv(smem, bid, tid, xin, nullptr, nullptr, nullptr, wfA, A1, qf, kf, vf);
    gsync(bar);
    st_attn(smem, bid, tid, qf, kf, vf, att);
    gsync(bar);
    st_proj(smem, bid, tid, att, wfA + 12288, A3, xin, nullptr, nullptr, nullptr,
            bufB, stats + 0);
    gsync(bar);
    st_ffn(smem, bid, tid, bufB, stats + 0, A8, A9, wfA + 16384, A5, wfA + 32768, A7,
           bufB, stats + 16);
    gsync(bar);
    // ---- block B (LN_a2 + roll fused into consumers) ----
    st_qkv(smem, bid, tid, bufB, stats + 16, A10, A11, wfB, B1, qf, kf, vf);
    gsync(bar);
    st_attn(smem, bid, tid, qf, kf, vf, att);
    gsync(bar);
    st_proj(smem, bid, tid, att, wfB + 12288, B3, bufB, stats + 16, A10, A11,
            bufA, stats + 32);
    gsync(bar);
    st_ffn(smem, bid, tid, bufA, stats + 32, B8, B9, wfB + 16384, B5, wfB + 32768, B7,
           bufA, stats + 48);
    gsync(bar);
    // ---- final LN_b2 + roll ----
    st_lnfinal(bid, tid, bufA, B10, B11, stats + 48, dout);
}

extern "C" void kernel_launch(void* const* d_in, const int* in_sizes, int n_in,
                              void* d_out, int out_size, void* d_ws, size_t ws_size,
                              hipStream_t stream) {
    const float* xin = (const float*)d_in[0];

    float* bufA  = (float*)d_ws;
    float* bufB  = bufA + S;
    float* stats = bufB + S;                        // 64 floats
    unsigned* bar = (unsigned*)(stats + 64);        // 16 uints
    short* qf    = (short*)(bar + 16);              // [NBWH][52][64][4]
    short* kf    = qf + (size_t)NBWH*FRAG_BWH;
    short* vf    = kf + (size_t)NBWH*FRAG_BWH;
    short* att   = vf + (size_t)NBWH*FRAG_BWH;      // [32][Nn][64] bf16
    short* wf    = att + (size_t)32*Nn*64;          // weight frags, 2 layers

    const float* A0  = (const float*)d_in[1];
    const float* A1  = (const float*)d_in[2];
    const float* A2  = (const float*)d_in[3];
    const float* A3  = (const float*)d_in[4];
    const float* A4  = (const float*)d_in[5];
    const float* A5  = (const float*)d_in[6];
    const float* A6  = (const float*)d_in[7];
    const float* A7  = (const float*)d_in[8];
    const float* A8  = (const float*)d_in[9];
    const float* A9  = (const float*)d_in[10];
    const float* A10 = (const float*)d_in[11];
    const float* A11 = (const float*)d_in[12];
    const float* B0  = (const float*)d_in[13];
    const float* B1  = (const float*)d_in[14];
    const float* B2  = (const float*)d_in[15];
    const float* B3  = (const float*)d_in[16];
    const float* B4  = (const float*)d_in[17];
    const float* B5  = (const float*)d_in[18];
    const float* B6  = (const float*)d_in[19];
    const float* B7  = (const float*)d_in[20];
    const float* B8  = (const float*)d_in[21];
    const float* B9  = (const float*)d_in[22];
    const float* B10 = (const float*)d_in[23];
    const float* B11 = (const float*)d_in[24];

    prep_kernel<<<416, 256, 0, stream>>>(A0, A2, A4, A6, B0, B2, B4, B6,
                                         wf, stats, bar, qf, kf, vf);
    mega_kernel<<<NBLK, 1024, 0, stream>>>(xin, bufA, bufB, stats, bar,
                                           wf, qf, kf, vf, att,
                                           A1, A3, A5, A7, A8, A9, A10, A11,
                                           B1, B3, B5, B7, B8, B9, B10, B11,
                                           (float*)d_out);
}

// Round 12
// 297.794 us; speedup vs baseline: 1.4716x; 1.4716x over previous
//
#include <hip/hip_runtime.h>
#include <hip/hip_bf16.h>

#define Bb  8
#define Cc  64
#define Tt  16
#define Vv  207
#define Hh  8
#define DH  8
#define NW  4
#define WSZ 4
#define Nn  (WSZ*Vv)       // 828
#define NP  832
#define TV  (Tt*Vv)        // 3312
#define CTV (Cc*Tt*Vv)     // 211968
#define S   (Bb*CTV)       // 1695744
#define NBWH (Bb*NW*Hh)    // 256
#define EPSF 1e-5f
#define QSCALE 0.51006971401146f    // log2(e)/sqrt(8) folded into Q
#define FRAG_BWH (52*64*4)          // 13312 shorts per bwh
#define LAYER_WSZ 49152             // qkv 12288 + proj 4096 + w1 16384 + w2 16384 frags

typedef __attribute__((ext_vector_type(4))) short bf16x4;
typedef __attribute__((ext_vector_type(4))) float f32x4;
typedef __attribute__((ext_vector_type(2))) unsigned int u32x2;
typedef __attribute__((ext_vector_type(4))) unsigned int u32x4;

static __device__ __forceinline__ short f2bf(float f) {
    union { float f; unsigned u; } v; v.f = f;
    unsigned r = (v.u + 0x7FFFu + ((v.u >> 16) & 1u)) >> 16;  // RNE
    return (short)r;
}

// cheap pack: round-half-up (bias cancels in softmax; fine elsewhere too)
static __device__ __forceinline__ bf16x4 pack4(float a, float b, float c, float d) {
    unsigned ua = __builtin_bit_cast(unsigned, a) + 0x8000u;
    unsigned ub = __builtin_bit_cast(unsigned, b) + 0x8000u;
    unsigned uc = __builtin_bit_cast(unsigned, c) + 0x8000u;
    unsigned ud = __builtin_bit_cast(unsigned, d) + 0x8000u;
    u32x2 t;
    t[0] = (ua >> 16) | (ub & 0xFFFF0000u);
    t[1] = (uc >> 16) | (ud & 0xFFFF0000u);
    return __builtin_bit_cast(bf16x4, t);
}

// ---------------- prep (merged): weights->frags, q/k/v const regions, stats zero ----------------
// grid = 416 x 256, grid-stride
__global__ void prep_kernel(const float* __restrict__ qa, const float* __restrict__ pa,
                            const float* __restrict__ w1a, const float* __restrict__ w2a,
                            const float* __restrict__ qbw, const float* __restrict__ pbw,
                            const float* __restrict__ w1b, const float* __restrict__ w2b,
                            short* __restrict__ wf, float* __restrict__ stats,
                            short* __restrict__ qf, short* __restrict__ kf,
                            short* __restrict__ vf) {
    int i0 = blockIdx.x*256 + threadIdx.x;
    if (i0 < 64) stats[i0] = 0.f;
    for (int i = i0; i < 24576; i += 416*256) {
        int l = i / 12288; int f = i % 12288;
        const float* qw = l ? qbw : qa;
        const float* pw = l ? pbw : pa;
        const float* w1 = l ? w1b : w1a;
        const float* w2 = l ? w2b : w2a;
        short* dst = wf + l*LAYER_WSZ;
        bf16x4 out;
        if (f < 3072) {
            int s = f; int nt = s>>8; int kc = (s>>6)&3; int ln = s&63;
            int li = ln&15; int q = ln>>4;
            #pragma unroll
            for (int j = 0; j < 4; ++j) out[j] = f2bf(qw[(kc*16+q*4+j)*192 + nt*16+li]);
            *((bf16x4*)&dst[s*4]) = out;
        } else if (f < 4096) {
            int s = f-3072; int nt = s>>8; int kc = (s>>6)&3; int ln = s&63;
            int li = ln&15; int q = ln>>4;
            #pragma unroll
            for (int j = 0; j < 4; ++j) out[j] = f2bf(pw[(kc*16+q*4+j)*64 + nt*16+li]);
            *((bf16x4*)&dst[12288 + s*4]) = out;
        } else if (f < 8192) {
            int s = f-4096; int nt = s>>8; int kc = (s>>6)&3; int ln = s&63;
            int li = ln&15; int q = ln>>4;
            #pragma unroll
            for (int j = 0; j < 4; ++j) out[j] = f2bf(w1[(kc*16+q*4+j)*256 + nt*16+li]);
            *((bf16x4*)&dst[16384 + s*4]) = out;
        } else {
            int s = f-8192; int nt = s>>8; int ct = (s>>6)&3; int ln = s&63;
            int li = ln&15; int q = ln>>4;
            #pragma unroll
            for (int j = 0; j < 4; ++j) out[j] = f2bf(w2[(nt*16+q*4+j)*64 + ct*16+li]);
            *((bf16x4*)&dst[32768 + s*4]) = out;
        }
    }
    // q/k frag lanes 32..63 zero; v frag l15==8 -> 1.0, l15 in 9..15 -> 0
    for (int i = i0; i < NBWH*1664; i += 416*256) {
        int bwh = i / 1664; int rest = i % 1664;
        int nt = rest >> 5; int u = rest & 31;
        size_t base = (size_t)bwh*FRAG_BWH + nt*256;
        *((u32x2*)&qf[base + (32+u)*4]) = (u32x2){0u,0u};
        *((u32x2*)&kf[base + (32+u)*4]) = (u32x2){0u,0u};
        int vlane = (u>>3)*16 + 8 + (u&7);
        short v = ((u&7) == 0) ? (short)0x3F80 : (short)0;
        bf16x4 vv4 = {v,v,v,v};
        *((bf16x4*)&vf[base + vlane*4]) = vv4;
    }
}

// ---------------- QKV: MFMA GEMM + optional fused LN2(+roll); frag-ordered outputs ----------------
// grid = 416 blocks, 256 threads
__global__ __launch_bounds__(256) void qkv_kernel(const float* __restrict__ src,
        const float* __restrict__ st, const float* __restrict__ g, const float* __restrict__ be,
        const short* __restrict__ wfq, const float* __restrict__ bias,
        short* __restrict__ qf, short* __restrict__ kf, short* __restrict__ vf) {
    __shared__ short wqs[12288];    // 24 KB weight frags
    __shared__ float bqs[192];
    __shared__ short os[64*196];    // 24.5 KB transpose buffer [pos][ch]
    int tid = threadIdx.x;
    int b = blockIdx.x / 52;
    int r0 = (blockIdx.x % 52) * 64;
    const float* xb = src + (size_t)b*CTV;
    {
        const u32x2* wsrc = (const u32x2*)wfq;
        u32x2* wdst = (u32x2*)wqs;
        for (int s = tid; s < 3072; s += 256) wdst[s] = wsrc[s];
    }
    if (tid < 192) bqs[tid] = bias[tid];
    __syncthreads();

    int lane = tid & 63; int wv = tid >> 6;
    int l15 = lane & 15; int quad = lane >> 4;
    int r = r0 + wv*16 + l15;
    int rc = (r < TV) ? r : TV-1;
    int t = rc / Vv; int vv = rc - t*Vv;
    float mean = 0.f, rstd = 0.f; int off;
    if (st) {
        mean = st[b*2] * (1.0f/CTV);
        float var = st[b*2+1] * (1.0f/CTV) - mean*mean;
        rstd = rsqrtf(var + EPSF);
        off = ((t+2)&15)*Vv + vv;       // roll(-2): read source at t+2
    } else off = rc;

    bf16x4 xf[4];
    #pragma unroll
    for (int kc = 0; kc < 4; ++kc) {
        #pragma unroll
        for (int j = 0; j < 4; ++j) {
            int idx = (kc*16 + quad*4 + j)*TV + off;
            float xv = xb[idx];
            if (st) xv = (xv - mean)*rstd*g[idx] + be[idx];
            xf[kc][j] = f2bf(xv);
        }
    }

    f32x4 accv[12];
    #pragma unroll
    for (int nt = 0; nt < 12; ++nt) {
        float4 bb = *((const float4*)&bqs[nt*16 + quad*4]);
        f32x4 acc = {bb.x, bb.y, bb.z, bb.w};
        #pragma unroll
        for (int kc = 0; kc < 4; ++kc) {
            bf16x4 wf2 = *((const bf16x4*)&wqs[((nt*4 + kc)*64 + lane)*4]);
            acc = __builtin_amdgcn_mfma_f32_16x16x16bf16_1k(wf2, xf[kc], acc, 0, 0, 0);
        }
        accv[nt] = acc;
    }

    // transpose to LDS: os[pos*196 + ch], ch = nt*16 + quad*4 + j
    int pos = wv*16 + l15;
    #pragma unroll
    for (int nt = 0; nt < 12; ++nt) {
        f32x4 a = accv[nt];
        bf16x4 pk = (nt < 4) ? pack4(a[0]*QSCALE, a[1]*QSCALE, a[2]*QSCALE, a[3]*QSCALE)
                             : pack4(a[0], a[1], a[2], a[3]);
        *((bf16x4*)&os[pos*196 + nt*16 + quad*4]) = pk;
    }
    __syncthreads();

    // store phase: frag-ordered outputs, coalesced 8B stores for q/k
    int pp = tid & 63;
    int rr = r0 + pp;
    bool pv = rr < TV;
    int rrc = pv ? rr : TV-1;
    int t4 = rrc / Vv; int vv4 = rrc - t4*Vv;
    int n2 = (t4 & 3)*Vv + vv4;
    int nt2 = n2 >> 4; int l15n = n2 & 15;
    int quadn = (n2 & 15) >> 2; int jn = n2 & 3;
    int wbase = (b*NW + (t4 >> 2))*Hh;
    if (pv) {
        #pragma unroll
        for (int i = 0; i < 2; ++i) {
            int h = i*4 + wv;
            size_t fb = ((size_t)(wbase+h)*52 + nt2)*256;
            bf16x4 q0 = *((const bf16x4*)&os[pp*196 + h*8]);
            bf16x4 q1 = *((const bf16x4*)&os[pp*196 + h*8 + 4]);
            *((bf16x4*)&qf[fb + l15n*4])        = q0;
            *((bf16x4*)&qf[fb + (16 + l15n)*4]) = q1;
            bf16x4 k0 = *((const bf16x4*)&os[pp*196 + 64 + h*8]);
            bf16x4 k1 = *((const bf16x4*)&os[pp*196 + 64 + h*8 + 4]);
            *((bf16x4*)&kf[fb + l15n*4])        = k0;
            *((bf16x4*)&kf[fb + (16 + l15n)*4]) = k1;
        }
        #pragma unroll
        for (int i = 0; i < 16; ++i) {
            int hd = i*4 + wv;
            int h = hd >> 3; int d = hd & 7;
            vf[(((size_t)(wbase+h)*52 + nt2)*64 + quadn*16 + d)*4 + jn]
                = os[pp*196 + 128 + hd];
        }
    }
}

// ---------------- Flash MFMA attention: frag-resident K/V in LDS, conflict-free ----------------
// grid = 256 blocks, 1024 threads (16 waves; wave wv owns m-tiles wv+16*i)
__global__ __launch_bounds__(1024) void attn_kernel(const short* __restrict__ qf,
        const short* __restrict__ kf, const short* __restrict__ vf,
        short* __restrict__ att) {
    __shared__ short ks2[FRAG_BWH];   // 26.6 KB
    __shared__ short vs2[FRAG_BWH];   // 26.6 KB
    int bwh = blockIdx.x;
    int tid = threadIdx.x;
    int lane = tid & 63;
    int wv = tid >> 6;
    int quad = lane >> 4;
    int l15 = lane & 15;

    {
        const u32x4* kg = (const u32x4*)(kf + (size_t)bwh*FRAG_BWH);
        const u32x4* vg = (const u32x4*)(vf + (size_t)bwh*FRAG_BWH);
        u32x4* kd = (u32x4*)ks2; u32x4* vd = (u32x4*)vs2;
        for (int idx = tid; idx < 1664; idx += 1024) { kd[idx] = kg[idx]; vd[idx] = vg[idx]; }
    }
    __syncthreads();

    int nm = (wv < 4) ? 4 : 3;
    const short* qbase = qf + (size_t)bwh*FRAG_BWH;
    bf16x4 aq[4];
    f32x4 oacc[4];
    #pragma unroll
    for (int i = 0; i < 4; ++i) {
        aq[i] = (bf16x4){0,0,0,0};
        oacc[i] = (f32x4){0.f,0.f,0.f,0.f};
        if (i < nm)
            aq[i] = *(const bf16x4*)(qbase + ((wv + 16*i)*256 + lane*4));
    }

    for (int nt = 0; nt < 52; ++nt) {
        bf16x4 ak = *(const bf16x4*)&ks2[nt*256 + lane*4];
        bf16x4 av = *(const bf16x4*)&vs2[nt*256 + lane*4];
        bool mask = (nt == 51) && (quad == 3);   // pad keys n=828..831
        #pragma unroll
        for (int i = 0; i < 4; ++i) {
            if (i < nm) {
                f32x4 s = __builtin_amdgcn_mfma_f32_16x16x16bf16_1k(
                              ak, aq[i], (f32x4){0.f,0.f,0.f,0.f}, 0, 0, 0);
                bf16x4 pb = pack4(__builtin_amdgcn_exp2f(s[0]), __builtin_amdgcn_exp2f(s[1]),
                                  __builtin_amdgcn_exp2f(s[2]), __builtin_amdgcn_exp2f(s[3]));
                if (mask) pb = (bf16x4){0,0,0,0};
                oacc[i] = __builtin_amdgcn_mfma_f32_16x16x16bf16_1k(av, pb, oacc[i], 0, 0, 0);
            }
        }
    }
    int h = bwh & 7; int bw = bwh >> 3;
    #pragma unroll
    for (int i = 0; i < 4; ++i) {
        if (i < nm) {
            float ls = __shfl(oacc[i][0], 32 + l15, 64);   // l-sum = O row 8
            float inv = 1.f / ls;
            int m = (wv + 16*i)*16 + l15;
            if (quad < 2 && m < Nn) {
                bf16x4 ov = pack4(oacc[i][0]*inv, oacc[i][1]*inv,
                                  oacc[i][2]*inv, oacc[i][3]*inv);
                *((bf16x4*)&att[((size_t)bw*Nn + m)*Cc + h*DH + quad*4]) = ov;
            }
        }
    }
}

// ---------------- Proj: MFMA + residual (optional fused LN2+roll) + LN stats ----------------
__global__ __launch_bounds__(256) void proj_kernel(const short* __restrict__ att,
        const short* __restrict__ wfp, const float* __restrict__ bo,
        const float* __restrict__ resid,
        const float* __restrict__ st, const float* __restrict__ g, const float* __restrict__ be,
        float* __restrict__ out, float* __restrict__ stats) {
    __shared__ short wos[4096];     // 8 KB
    __shared__ float bos[64];
    __shared__ float r1[256], r2[256];
    int tid = threadIdx.x;
    int b = blockIdx.x / 52;
    int r0 = (blockIdx.x % 52) * 64;
    const float* xb = resid + (size_t)b*CTV;
    {
        const u32x2* wsrc = (const u32x2*)wfp;
        u32x2* wdst = (u32x2*)wos;
        for (int s = tid; s < 1024; s += 256) wdst[s] = wsrc[s];
    }
    if (tid < 64) bos[tid] = bo[tid];
    __syncthreads();

    int lane = tid & 63; int wv = tid >> 6;
    int l15 = lane & 15; int quad = lane >> 4;
    int r = r0 + wv*16 + l15;
    bool valid = r < TV;
    int rc = valid ? r : TV-1;
    int t = rc / Vv; int vv = rc - t*Vv;
    int n = (t & 3)*Vv + vv;
    int bw = b*NW + (t >> 2);
    const short* arow = att + ((size_t)bw*Nn + n)*Cc;
    bf16x4 af[4];
    #pragma unroll
    for (int kc = 0; kc < 4; ++kc)
        af[kc] = *((const bf16x4*)&arow[kc*16 + quad*4]);

    f32x4 acc[4];
    #pragma unroll
    for (int nt = 0; nt < 4; ++nt) {
        float4 bb = *((const float4*)&bos[nt*16 + quad*4]);
        acc[nt] = (f32x4){bb.x, bb.y, bb.z, bb.w};
        #pragma unroll
        for (int kc = 0; kc < 4; ++kc) {
            bf16x4 wf2 = *((const bf16x4*)&wos[((nt*4 + kc)*64 + lane)*4]);
            acc[nt] = __builtin_amdgcn_mfma_f32_16x16x16bf16_1k(wf2, af[kc], acc[nt], 0, 0, 0);
        }
    }
    float mean = 0.f, rstd = 0.f; int off;
    if (st) {
        mean = st[b*2] * (1.0f/CTV);
        float var = st[b*2+1] * (1.0f/CTV) - mean*mean;
        rstd = rsqrtf(var + EPSF);
        off = ((t+2)&15)*Vv + vv;
    } else off = rc;
    float s1 = 0.f, s2 = 0.f;
    if (valid) {
        #pragma unroll
        for (int nt = 0; nt < 4; ++nt) {
            #pragma unroll
            for (int j = 0; j < 4; ++j) {
                int c_out = nt*16 + quad*4 + j;
                int ridx = c_out*TV + off;
                float xv = xb[ridx];
                if (st) xv = (xv - mean)*rstd*g[ridx] + be[ridx];
                float val = acc[nt][j] + xv;
                out[(size_t)b*CTV + (size_t)c_out*TV + r] = val;
                s1 += val; s2 += val*val;
            }
        }
    }
    r1[tid] = s1; r2[tid] = s2;
    __syncthreads();
    for (int o = 128; o > 0; o >>= 1) {
        if (tid < o) { r1[tid] += r1[tid+o]; r2[tid] += r2[tid+o]; }
        __syncthreads();
    }
    if (tid == 0) { atomicAdd(&stats[b*2], r1[0]); atomicAdd(&stats[b*2+1], r2[0]); }
}

// ---------------- LayerNorm apply (+roll) — final output only ----------------
__global__ void ln_apply_kernel(const float* __restrict__ x,
                                const float* __restrict__ g,
                                const float* __restrict__ be,
                                const float* __restrict__ stats,
                                float* __restrict__ out,
                                int shift) {
    int idx = blockIdx.x*256 + threadIdx.x;
    if (idx >= S) return;
    int b = idx / CTV; int r = idx % CTV;
    int c = r / TV; int q2 = r % TV; int t = q2 / Vv; int vv = q2 % Vv;
    float mean = stats[b*2] * (1.0f/CTV);
    float var  = stats[b*2+1] * (1.0f/CTV) - mean*mean;
    float rstd = rsqrtf(var + EPSF);
    float val = (x[idx]-mean)*rstd*g[r] + be[r];
    int tout = (t - shift + Tt) % Tt;   // roll(-shift)
    size_t oidx = ((size_t)(b*Cc + c)*Tt + tout)*Vv + vv;
    out[oidx] = val;
}

// ---------------- FFN: fused LN1 on input, MFMA two-stage, residual, LN stats ----------------
__global__ __launch_bounds__(256) void ffn_kernel(const float* __restrict__ xin,
        const float* __restrict__ st, const float* __restrict__ g, const float* __restrict__ be,
        const short* __restrict__ wf1, const float* __restrict__ b1,
        const short* __restrict__ wf2g, const float* __restrict__ b2,
        float* __restrict__ out, float* __restrict__ stats) {
    __shared__ short w1s[16384];    // 32 KB
    __shared__ short w2s[16384];    // 32 KB
    __shared__ short xsf[4096];     // 8 KB
    __shared__ float b1s[256];
    __shared__ float b2s[64];
    __shared__ float r1s[256], r2s[256];
    int tid = threadIdx.x;
    int b = blockIdx.x / 52;
    int r0 = (blockIdx.x % 52) * 64;
    const float* xb = xin + (size_t)b*CTV;
    float mean = st[b*2] * (1.0f/CTV);
    float var  = st[b*2+1] * (1.0f/CTV) - mean*mean;
    float rstd = rsqrtf(var + EPSF);

    {
        const u32x2* s1p = (const u32x2*)wf1;
        const u32x2* s2p = (const u32x2*)wf2g;
        u32x2* d1 = (u32x2*)w1s; u32x2* d2 = (u32x2*)w2s;
        for (int s = tid; s < 4096; s += 256) { d1[s] = s1p[s]; d2[s] = s2p[s]; }
    }
    for (int s2 = tid; s2 < 1024; s2 += 256) {
        int wv2 = s2 >> 8; int kc = (s2 >> 6) & 3; int ln = s2 & 63;
        int l15 = ln & 15; int quad = ln >> 4;
        int r = r0 + wv2*16 + l15; if (r >= TV) r = TV-1;
        bf16x4 f;
        #pragma unroll
        for (int j = 0; j < 4; ++j) {
            int idx = (kc*16 + quad*4 + j)*TV + r;
            f[j] = f2bf((xb[idx] - mean)*rstd*g[idx] + be[idx]);
        }
        *((bf16x4*)&xsf[s2*4]) = f;
    }
    b1s[tid] = b1[tid];
    if (tid < 64) b2s[tid] = b2[tid];
    __syncthreads();

    int lane = tid & 63; int wv = tid >> 6;
    int l15 = lane & 15; int quad = lane >> 4;
    bf16x4 xf[4];
    #pragma unroll
    for (int kc = 0; kc < 4; ++kc)
        xf[kc] = *((const bf16x4*)&xsf[((wv*4 + kc)*64 + lane)*4]);

    f32x4 oacc[4];
    #pragma unroll
    for (int ct = 0; ct < 4; ++ct) oacc[ct] = (f32x4){0.f,0.f,0.f,0.f};

    for (int nt = 0; nt < 16; ++nt) {
        float4 bb = *((const float4*)&b1s[nt*16 + quad*4]);
        f32x4 acc = {bb.x, bb.y, bb.z, bb.w};
        #pragma unroll
        for (int kc = 0; kc < 4; ++kc) {
            bf16x4 wfv = *((const bf16x4*)&w1s[((nt*4 + kc)*64 + lane)*4]);
            acc = __builtin_amdgcn_mfma_f32_16x16x16bf16_1k(wfv, xf[kc], acc, 0, 0, 0);
        }
        bf16x4 pf = pack4(fmaxf(acc[0], 0.f), fmaxf(acc[1], 0.f),
                          fmaxf(acc[2], 0.f), fmaxf(acc[3], 0.f));
        #pragma unroll
        for (int ct = 0; ct < 4; ++ct) {
            bf16x4 wfv2 = *((const bf16x4*)&w2s[((nt*4 + ct)*64 + lane)*4]);
            oacc[ct] = __builtin_amdgcn_mfma_f32_16x16x16bf16_1k(wfv2, pf, oacc[ct], 0, 0, 0);
        }
    }
    int r = r0 + wv*16 + l15;
    float s1 = 0.f, s2v = 0.f;
    if (r < TV) {
        #pragma unroll
        for (int ct = 0; ct < 4; ++ct) {
            #pragma unroll
            for (int j = 0; j < 4; ++j) {
                int c_out = ct*16 + quad*4 + j;
                int idx = c_out*TV + r;
                float xv = (xb[idx] - mean)*rstd*g[idx] + be[idx];
                float val = oacc[ct][j] + b2s[c_out] + xv;
                out[(size_t)b*CTV + idx] = val;
                s1 += val; s2v += val*val;
            }
        }
    }
    r1s[tid] = s1; r2s[tid] = s2v;
    __syncthreads();
    for (int o = 128; o > 0; o >>= 1) {
        if (tid < o) { r1s[tid] += r1s[tid+o]; r2s[tid] += r2s[tid+o]; }
        __syncthreads();
    }
    if (tid == 0) { atomicAdd(&stats[b*2], r1s[0]); atomicAdd(&stats[b*2+1], r2s[0]); }
}

extern "C" void kernel_launch(void* const* d_in, const int* in_sizes, int n_in,
                              void* d_out, int out_size, void* d_ws, size_t ws_size,
                              hipStream_t stream) {
    const float* xin = (const float*)d_in[0];

    float* bufA  = (float*)d_ws;
    float* bufB  = bufA + S;
    float* stats = bufB + S;                        // 64 floats
    short* qf    = (short*)(stats + 64);            // [NBWH][52][64][4]
    short* kf    = qf + (size_t)NBWH*FRAG_BWH;
    short* vf    = kf + (size_t)NBWH*FRAG_BWH;
    short* att   = vf + (size_t)NBWH*FRAG_BWH;      // [32][Nn][64] bf16
    short* wf    = att + (size_t)32*Nn*64;          // weight frags, 2 layers

    const float* A0  = (const float*)d_in[1];
    const float* A1  = (const float*)d_in[2];
    const float* A2  = (const float*)d_in[3];
    const float* A3  = (const float*)d_in[4];
    const float* A4  = (const float*)d_in[5];
    const float* A5  = (const float*)d_in[6];
    const float* A6  = (const float*)d_in[7];
    const float* A7  = (const float*)d_in[8];
    const float* A8  = (const float*)d_in[9];
    const float* A9  = (const float*)d_in[10];
    const float* A10 = (const float*)d_in[11];
    const float* A11 = (const float*)d_in[12];
    const float* B0  = (const float*)d_in[13];
    const float* B1  = (const float*)d_in[14];
    const float* B2  = (const float*)d_in[15];
    const float* B3  = (const float*)d_in[16];
    const float* B4  = (const float*)d_in[17];
    const float* B5  = (const float*)d_in[18];
    const float* B6  = (const float*)d_in[19];
    const float* B7  = (const float*)d_in[20];
    const float* B8  = (const float*)d_in[21];
    const float* B9  = (const float*)d_in[22];
    const float* B10 = (const float*)d_in[23];
    const float* B11 = (const float*)d_in[24];

    float* st1a = stats + 0;
    float* st2a = stats + 16;
    float* st1b = stats + 32;
    float* st2b = stats + 48;

    short* wfA = wf;
    short* wfB = wf + LAYER_WSZ;

    prep_kernel<<<416, 256, 0, stream>>>(A0, A2, A4, A6, B0, B2, B4, B6,
                                         wf, stats, qf, kf, vf);

    // ---- block A (input raw) ----
    qkv_kernel<<<Bb*52, 256, 0, stream>>>(xin, nullptr, nullptr, nullptr,
                                          wfA, A1, qf, kf, vf);
    attn_kernel<<<NBWH, 1024, 0, stream>>>(qf, kf, vf, att);
    proj_kernel<<<Bb*52, 256, 0, stream>>>(att, wfA + 12288, A3, xin,
                                           nullptr, nullptr, nullptr, bufB, st1a);
    ffn_kernel<<<Bb*52, 256, 0, stream>>>(bufB, st1a, A8, A9,
                                          wfA + 16384, A5, wfA + 32768, A7, bufB, st2a);
    // ---- block B (input = LN_a2(bufB) rolled, fused into consumers) ----
    qkv_kernel<<<Bb*52, 256, 0, stream>>>(bufB, st2a, A10, A11,
                                          wfB, B1, qf, kf, vf);
    attn_kernel<<<NBWH, 1024, 0, stream>>>(qf, kf, vf, att);
    proj_kernel<<<Bb*52, 256, 0, stream>>>(att, wfB + 12288, B3, bufB,
                                           st2a, A10, A11, bufA, st1b);
    ffn_kernel<<<Bb*52, 256, 0, stream>>>(bufA, st1b, B8, B9,
                                          wfB + 16384, B5, wfB + 32768, B7, bufA, st2b);
    // ---- final LN_b2 + roll -> d_out ----
    ln_apply_kernel<<<(S+255)/256, 256, 0, stream>>>(bufA, B10, B11, st2b, (float*)d_out, WSZ/2);
}